// Round 10
// baseline (977.763 us; speedup 1.0000x reference)
//
#include <hip/hip_runtime.h>
#include <hip/hip_bf16.h>
#include <cstdint>
#include <cstddef>

#define SEQ_LEN 1024
#define NBATCH  2
#define MROWS   2048          // NBATCH*SEQ_LEN, row index m = b*SEQ_LEN + s
#define DMODEL  768
#define DINNER  1536
#define DTRANK  48
#define DSTATE  16
#define NLAYERS 4
#define NVOCAB  32000
#define XPROJ_N 80            // DTRANK + 2*DSTATE
#define NCHUNK  16
#define CHUNK   64            // SEQ_LEN / NCHUNK
#define GROUPS  (NBATCH * DINNER)          // 3072
#define SCANW   (GROUPS * DSTATE)          // 49152
#define XSPLIT  8             // xproj split-K factor

typedef __attribute__((ext_vector_type(4))) float f32x4;
typedef __attribute__((ext_vector_type(8))) short s16x8;
using bf16 = __hip_bfloat16;

__device__ __forceinline__ float b2f(bf16 v){ return __bfloat162float(v); }
__device__ __forceinline__ bf16  f2b(float v){ return __float2bfloat16(v); }
__device__ __forceinline__ short f2bs(float v){
  return (short)__builtin_bit_cast(unsigned short, __float2bfloat16(v));
}

// async global->LDS, 16B per lane; LDS dest = (wave-uniform base) + lane*16
__device__ __forceinline__ void glds16(const ushort* g, ushort* l) {
  __builtin_amdgcn_global_load_lds(
      (const __attribute__((address_space(1))) void*)g,
      (__attribute__((address_space(3))) void*)l,
      16, 0, 0);
}

// ---------------- merged f32 -> bf16 convert for all 5 weight tensors ----------------
#define CVT_E0 6144000            // emb     24,576,000 elems /4
#define CVT_E1 (CVT_E0 + 2359296) // + W_in   9,437,184 /4
#define CVT_E2 (CVT_E1 + 1179648) // + W_out  4,718,592 /4
#define CVT_E3 (CVT_E2 + 122880)  // + W_xproj  491,520 /4
#define CVT_E4 (CVT_E3 + 73728)   // + W_dt     294,912 /4
__global__ __launch_bounds__(256) void k_cvt5(
    const float* __restrict__ s0, const float* __restrict__ s1,
    const float* __restrict__ s2, const float* __restrict__ s3,
    const float* __restrict__ s4,
    ushort* __restrict__ d0, ushort* __restrict__ d1,
    ushort* __restrict__ d2, ushort* __restrict__ d3,
    ushort* __restrict__ d4)
{
  int i = blockIdx.x * 256 + threadIdx.x;
  const float* s; ushort* d; int base;
  if      (i < CVT_E0) { s = s0; d = d0; base = 0; }
  else if (i < CVT_E1) { s = s1; d = d1; base = CVT_E0; }
  else if (i < CVT_E2) { s = s2; d = d2; base = CVT_E1; }
  else if (i < CVT_E3) { s = s3; d = d3; base = CVT_E2; }
  else if (i < CVT_E4) { s = s4; d = d4; base = CVT_E3; }
  else return;
  int li = i - base;
  f32x4 v = *(const f32x4*)(s + (size_t)li * 4);
  ushort4 o;
  o.x = (ushort)f2bs(v[0]); o.y = (ushort)f2bs(v[1]);
  o.z = (ushort)f2bs(v[2]); o.w = (ushort)f2bs(v[3]);
  *(ushort4*)(d + (size_t)li * 4) = o;
}

// ---------------- sum XSPLIT f32 partials -> bf16 (xproj split-K reduce) ----------------
__global__ __launch_bounds__(256) void k_xsum(const float* __restrict__ p,
    ushort* __restrict__ out, int n4) {
  int i = blockIdx.x * 256 + threadIdx.x;
  if (i >= n4) return;
  f32x4 s = {};
#pragma unroll
  for (int z = 0; z < XSPLIT; z++) {
    f32x4 v = *(const f32x4*)(p + (size_t)z * (MROWS * XPROJ_N) + (size_t)i * 4);
    s[0] += v[0]; s[1] += v[1]; s[2] += v[2]; s[3] += v[3];
  }
  ushort4 o;
  o.x = (ushort)f2bs(s[0]); o.y = (ushort)f2bs(s[1]);
  o.z = (ushort)f2bs(s[2]); o.w = (ushort)f2bs(s[3]);
  *(ushort4*)(out + (size_t)i * 4) = o;
}

// ---------------- LN body shared by k_ln / k_embed_ln ----------------
__device__ __forceinline__ void ln_rows(const float v0[3], int t,
    const float* __restrict__ g, const float* __restrict__ b,
    bf16* __restrict__ outrow) {
  float s = 0.f, s2 = 0.f;
#pragma unroll
  for (int j = 0; j < 3; j++) { s += v0[j]; s2 += v0[j] * v0[j]; }
#pragma unroll
  for (int o = 32; o >= 1; o >>= 1) { s += __shfl_xor(s, o); s2 += __shfl_xor(s2, o); }
  __shared__ float red[8];
  int wave = t >> 6;
  if ((t & 63) == 0) { red[wave] = s; red[4 + wave] = s2; }
  __syncthreads();
  s  = red[0] + red[1] + red[2] + red[3];
  s2 = red[4] + red[5] + red[6] + red[7];
  float mean = s * (1.f / DMODEL);
  float var  = s2 * (1.f / DMODEL) - mean * mean;
  float rstd = rsqrtf(var + 1e-5f);
#pragma unroll
  for (int j = 0; j < 3; j++) {
    int d = t + j * 256;
    outrow[d] = f2b((v0[j] - mean) * rstd * g[d] + b[d]);
  }
}

// ---------------- LayerNorm over 768, f32 in -> bf16 out ----------------
__global__ __launch_bounds__(256) void k_ln(const float* __restrict__ x,
    bf16* __restrict__ out, const float* __restrict__ g, const float* __restrict__ b) {
  int m = blockIdx.x;
  const float* row = x + (size_t)m * DMODEL;
  int t = threadIdx.x;
  float v0[3];
#pragma unroll
  for (int j = 0; j < 3; j++) v0[j] = row[t + j * 256];
  ln_rows(v0, t, g, b, out + (size_t)m * DMODEL);
}

// ---------------- fused embedding gather + layer-0 LN ----------------
__global__ __launch_bounds__(256) void k_embed_ln(const int* __restrict__ tok,
    const float* __restrict__ emb, float* __restrict__ x,
    bf16* __restrict__ out, const float* __restrict__ g, const float* __restrict__ b) {
  int m = blockIdx.x;
  const float* row = emb + (size_t)tok[m] * DMODEL;
  int t = threadIdx.x;
  float v0[3];
#pragma unroll
  for (int j = 0; j < 3; j++) {
    v0[j] = row[t + j * 256];
    x[(size_t)m * DMODEL + t + j * 256] = v0[j];   // residual base
  }
  ln_rows(v0, t, g, b, out + (size_t)m * DMODEL);
}

// ---------------- 128x128 GEMM, 8 waves (W_in / W_out) ----------------
// C[M,N] = A[M,K] * B[N,K]^T. 512 threads, 8 waves as 4Mx2N, each wave 32x64.
// Depth-1 prefetch, counted vmcnt(2). OMODE: 0 f32, 1 f32 atomicAdd, 2 bf16.
template<bool HAS_BIAS, int OMODE>
__global__ __launch_bounds__(512, 4) void k_gemm128(
    const ushort* __restrict__ A, int lda,
    const ushort* __restrict__ B, int ldb,
    void* __restrict__ C, int ldc,
    const float* __restrict__ bias,
    int M, int N, int K)
{
  __shared__ ushort As[2][128 * 32];
  __shared__ ushort Bs[2][128 * 32];
  const int t = threadIdx.x;             // 0..511
  const int lane = t & 63;
  const int wave = t >> 6;               // 0..7
  const int tile_m = blockIdx.x * 128;
  const int tile_n = blockIdx.y * 128;
  const int kper = K / gridDim.z;
  const int kb = blockIdx.z * kper;
  const int ke = kb + kper;
  const int wr = (wave >> 1) * 32;       // 4 M-groups of 32
  const int wc = (wave & 1) * 64;        // 2 N-groups of 64

  f32x4 acc[2][4] = {};

  const int sr = wave * 16 + (lane >> 2);
  const int sc = (lane & 3) * 8;
  const ushort* gA = A + (size_t)(tile_m + sr) * lda + sc + kb;
  const ushort* gB = B + (size_t)(tile_n + sr) * ldb + sc + kb;

  const int fr = lane & 15;
  const int kk = (lane >> 4) * 8;

  auto stage = [&](int bb) {
    glds16(gA, &As[bb][wave * 512]);
    glds16(gB, &Bs[bb][wave * 512]);
    gA += 32; gB += 32;
  };

  stage(0);
  int cur = 0;

  for (int k0 = kb; k0 < ke; k0 += 32) {
    if (k0 + 32 < ke) {
      stage(cur ^ 1);                                   // prefetch next tile
      asm volatile("s_waitcnt vmcnt(2)" ::: "memory");  // drain current tile only
    } else {
      asm volatile("s_waitcnt vmcnt(0)" ::: "memory");
    }
    __builtin_amdgcn_s_barrier();

    s16x8 a[2], b[4];
#pragma unroll
    for (int m = 0; m < 2; m++)
      a[m] = *(const s16x8*)&As[cur][(wr + m * 16 + fr) * 32 + kk];
#pragma unroll
    for (int n = 0; n < 4; n++)
      b[n] = *(const s16x8*)&Bs[cur][(wc + n * 16 + fr) * 32 + kk];
#pragma unroll
    for (int m = 0; m < 2; m++)
#pragma unroll
      for (int n = 0; n < 4; n++)
        acc[m][n] = __builtin_amdgcn_mfma_f32_16x16x32_bf16(a[m], b[n], acc[m][n], 0, 0, 0);

    __builtin_amdgcn_s_barrier();
    cur ^= 1;
  }

  const int rq = (lane >> 4) * 4;
#pragma unroll
  for (int m = 0; m < 2; m++)
#pragma unroll
    for (int n = 0; n < 4; n++) {
      int colg = tile_n + wc + n * 16 + fr;
      float bv = HAS_BIAS ? bias[colg] : 0.f;
#pragma unroll
      for (int r = 0; r < 4; r++) {
        int rowg = tile_m + wr + m * 16 + rq + r;
        size_t idx = (size_t)rowg * ldc + colg;
        float v = acc[m][n][r] + bv;
        if constexpr (OMODE == 0) ((float*)C)[idx] = v;
        else if constexpr (OMODE == 1) atomicAdd((float*)C + idx, v);
        else ((bf16*)C)[idx] = f2b(v);
      }
    }
}

// ---------------- 256x256 GEMM (head): 16 waves (1024 thr), each 64x64 ----------------
// Same verified 2-phase skeleton; geometry raises staging intensity 1.5x vs
// 256x128 (32KB loaded / 256 block-MFMA per K-step) and halves B traffic per
// output. acc 4x4 (~114 regs) -> 4 waves/SIMD -> 16 waves/CU resident.
// Staging: ONE glds16 per matrix per K-step (1024 thr x 16B = 256x32 bf16).
// Counted vmcnt(2). Grid (M/256, N/256) = (8,125) = 1000 blocks. No swizzle
// (twice shown FETCH-reduction does not pay on this kernel).
template<bool HAS_BIAS>
__global__ __launch_bounds__(1024, 1) void k_gemmhead(
    const ushort* __restrict__ A, int lda,
    const ushort* __restrict__ B, int ldb,
    float* __restrict__ C, int ldc,
    const float* __restrict__ bias,
    int M, int N, int K)
{
  __shared__ ushort As[2][256 * 32];     // 16 KB per buffer
  __shared__ ushort Bs[2][256 * 32];
  const int t = threadIdx.x;             // 0..1023
  const int lane = t & 63;
  const int wave = t >> 6;               // 0..15
  const int tile_m = blockIdx.x * 256;
  const int tile_n = blockIdx.y * 256;
  const int wr = (wave >> 2) * 64;       // 4 M-groups of 64
  const int wc = (wave & 3) * 64;        // 4 N-groups of 64

  f32x4 acc[4][4] = {};

  // staging: wave w covers rows w*16..+15 of the 256x32 tile; lane l ->
  // row +(l>>2), col (l&3)*8; LDS dest = base + w*512 ushorts (+ lane*16B HW).
  const int sr = wave * 16 + (lane >> 2);
  const int sc = (lane & 3) * 8;
  const ushort* gA = A + (size_t)(tile_m + sr) * lda + sc;
  const ushort* gB = B + (size_t)(tile_n + sr) * ldb + sc;

  const int fr = lane & 15;
  const int kk = (lane >> 4) * 8;

  auto stage = [&](int bb) {
    glds16(gA, &As[bb][wave * 512]);
    glds16(gB, &Bs[bb][wave * 512]);
    gA += 32; gB += 32;
  };

  stage(0);
  int cur = 0;

  for (int k0 = 0; k0 < K; k0 += 32) {
    if (k0 + 32 < K) {
      stage(cur ^ 1);                                   // prefetch next tile
      asm volatile("s_waitcnt vmcnt(2)" ::: "memory");  // drain current tile only
    } else {
      asm volatile("s_waitcnt vmcnt(0)" ::: "memory");
    }
    __builtin_amdgcn_s_barrier();

    s16x8 a[4], b[4];
#pragma unroll
    for (int m = 0; m < 4; m++)
      a[m] = *(const s16x8*)&As[cur][(wr + m * 16 + fr) * 32 + kk];
#pragma unroll
    for (int n = 0; n < 4; n++)
      b[n] = *(const s16x8*)&Bs[cur][(wc + n * 16 + fr) * 32 + kk];
#pragma unroll
    for (int m = 0; m < 4; m++)
#pragma unroll
      for (int n = 0; n < 4; n++)
        acc[m][n] = __builtin_amdgcn_mfma_f32_16x16x32_bf16(a[m], b[n], acc[m][n], 0, 0, 0);

    __builtin_amdgcn_s_barrier();
    cur ^= 1;
  }

  const int rq = (lane >> 4) * 4;
#pragma unroll
  for (int m = 0; m < 4; m++)
#pragma unroll
    for (int n = 0; n < 4; n++) {
      int colg = tile_n + wc + n * 16 + fr;
      float bv = HAS_BIAS ? bias[colg] : 0.f;
#pragma unroll
      for (int r = 0; r < 4; r++) {
        int rowg = tile_m + wr + m * 16 + rq + r;
        C[(size_t)rowg * ldc + colg] = acc[m][n][r] + bv;
      }
    }
}

// ---------------- small GEMM (bounds-checked 64x64): C = A * W^T, bf16 inputs ----------------
// MODE: 0 = bf16 out
//       2 = dt-fused: sp=softplus(acc+bias[col]) -> dtf[idx]=sp (f32),
//           dtx[idx]=bf16(sp*xcb[idx])
//       3 = f32 partial out at slice blockIdx.z (xproj split-K; stride MROWS*XPROJ_N)
template<int MODE>
__global__ __launch_bounds__(256) void k_gemm(
    const ushort* __restrict__ A, int lda,
    const ushort* __restrict__ W, int ldw,
    void* __restrict__ Cout, int ldc,
    int M, int N, int K,
    const float* __restrict__ bias,
    const bf16* __restrict__ xcb,
    bf16* __restrict__ dtxp)
{
  __shared__ ushort As[64][40];
  __shared__ ushort Ws[64][40];
  const int tile_m = blockIdx.x * 64;
  const int tile_n = blockIdx.y * 64;
  const int t = threadIdx.x;
  const int lane = t & 63;
  const int wave = t >> 6;
  const int wr = (wave >> 1) * 32;
  const int wc = (wave & 1) * 32;
  f32x4 acc[2][2] = {};

  const int kper = ((K + gridDim.z - 1) / gridDim.z + 31) & ~31;
  const int kb = blockIdx.z * kper;
  int ke = kb + kper; if (ke > K) ke = K;

  const int srow = t >> 2;
  const int scol = (t & 3) * 8;

  for (int k0 = kb; k0 < ke; k0 += 32) {
    {
      int gm = tile_m + srow, gk = k0 + scol;
      s16x8 v = {};
      if (gm < M) {
        if (gk + 8 <= K) v = *(const s16x8*)(A + (size_t)gm * lda + gk);
        else {
#pragma unroll
          for (int j = 0; j < 8; j++) if (gk + j < K) v[j] = (short)A[(size_t)gm * lda + gk + j];
        }
      }
      *(s16x8*)&As[srow][scol] = v;
    }
    {
      int gn = tile_n + srow, gk = k0 + scol;
      s16x8 v = {};
      if (gn < N) {
        if (gk + 8 <= K) v = *(const s16x8*)(W + (size_t)gn * ldw + gk);
        else {
#pragma unroll
          for (int j = 0; j < 8; j++) if (gk + j < K) v[j] = (short)W[(size_t)gn * ldw + gk + j];
        }
      }
      *(s16x8*)&Ws[srow][scol] = v;
    }
    __syncthreads();
    const int kk = (lane >> 4) * 8;
    const int fr = lane & 15;
    s16x8 a0 = *(const s16x8*)&As[wr + fr][kk];
    s16x8 a1 = *(const s16x8*)&As[wr + 16 + fr][kk];
    s16x8 b0 = *(const s16x8*)&Ws[wc + fr][kk];
    s16x8 b1 = *(const s16x8*)&Ws[wc + 16 + fr][kk];
    acc[0][0] = __builtin_amdgcn_mfma_f32_16x16x32_bf16(a0, b0, acc[0][0], 0, 0, 0);
    acc[0][1] = __builtin_amdgcn_mfma_f32_16x16x32_bf16(a0, b1, acc[0][1], 0, 0, 0);
    acc[1][0] = __builtin_amdgcn_mfma_f32_16x16x32_bf16(a1, b0, acc[1][0], 0, 0, 0);
    acc[1][1] = __builtin_amdgcn_mfma_f32_16x16x32_bf16(a1, b1, acc[1][1], 0, 0, 0);
    __syncthreads();
  }

  const int fr = lane & 15;
  const int rq = (lane >> 4) * 4;
#pragma unroll
  for (int i = 0; i < 2; i++)
#pragma unroll
    for (int j = 0; j < 2; j++) {
      int colg = tile_n + wc + j * 16 + fr;
#pragma unroll
      for (int r = 0; r < 4; r++) {
        int rowg = tile_m + wr + i * 16 + rq + r;
        if (rowg < M && colg < N) {
          float v = acc[i][j][r];
          size_t idx = (size_t)rowg * ldc + colg;
          if constexpr (MODE == 0) {
            ((bf16*)Cout)[idx] = f2b(v);
          } else if constexpr (MODE == 2) {
            v += bias[colg];
            float sp = (v > 20.f) ? v : log1pf(__expf(v));
            ((float*)Cout)[idx] = sp;
            dtxp[idx] = f2b(sp * b2f(xcb[idx]));
          } else {
            ((float*)Cout)[(size_t)blockIdx.z * (MROWS * XPROJ_N) + idx] = v;
          }
        }
      }
    }
}

// ---------------- causal depthwise conv (D_CONV=4) + bias + silu; bf16 in/out ----------------
__global__ __launch_bounds__(256) void k_conv(const bf16* __restrict__ xz,
    const float* __restrict__ w, const float* __restrict__ cb,
    bf16* __restrict__ xcb) {
  int id = blockIdx.x * 256 + threadIdx.x;          // MROWS*DINNER
  int m = id / DINNER, c = id - m * DINNER;
  int s = m & (SEQ_LEN - 1);
  float acc = cb[c];
#pragma unroll
  for (int k = 0; k < 4; k++) {
    int sp = s - 3 + k;
    if (sp >= 0) acc += w[c * 4 + k] * b2f(xz[(size_t)(m - 3 + k) * (2 * DINNER) + c]);
  }
  float sil = acc / (1.f + __expf(-acc));
  xcb[id] = f2b(sil);
}

// ---------------- chunked selective scan (3 kernels; per-wave-coalesced layout) ----------------
__global__ __launch_bounds__(256) void k_scan1(const float* __restrict__ dt,
    const bf16* __restrict__ dtx, const bf16* __restrict__ xdb,
    const float* __restrict__ A_log, float* __restrict__ aprod,
    float* __restrict__ hend) {
  int gid = blockIdx.x * 256 + threadIdx.x;     // SCANW*NCHUNK
  int n  = gid & 15;
  int t2 = gid >> 4;
  int j  = t2 / GROUPS;
  int cb = t2 - j * GROUPS;
  int c  = cb % DINNER;
  int b  = cb / DINNER;
  float Acn = -__expf(A_log[c * DSTATE + n]);
  float h = 0.f, ap = 1.f;
  int mbase = b * SEQ_LEN + j * CHUNK;
#pragma unroll 4
  for (int s = 0; s < CHUNK; s++) {
    int m = mbase + s;
    float dtv = dt[(size_t)m * DINNER + c];
    float dxv = b2f(dtx[(size_t)m * DINNER + c]);
    float Bv  = b2f(xdb[(size_t)m * XPROJ_N + DTRANK + n]);
    float dA  = __expf(dtv * Acn);
    h = h * dA + dxv * Bv;
    ap *= dA;
  }
  aprod[gid] = ap;
  hend[gid]  = h;
}

__global__ __launch_bounds__(256) void k_scan2(const float* __restrict__ aprod,
    const float* __restrict__ hend, float* __restrict__ hin) {
  int idx = blockIdx.x * 256 + threadIdx.x;     // SCANW
  float h = 0.f;
#pragma unroll
  for (int j = 0; j < NCHUNK; j++) {
    hin[(size_t)j * SCANW + idx] = h;
    h = aprod[(size_t)j * SCANW + idx] * h + hend[(size_t)j * SCANW + idx];
  }
}

__global__ __launch_bounds__(256) void k_scan3(const float* __restrict__ dt,
    const bf16* __restrict__ dtx, const bf16* __restrict__ xdb,
    const float* __restrict__ A_log, const float* __restrict__ hin,
    bf16* __restrict__ y) {
  int gid = blockIdx.x * 256 + threadIdx.x;     // SCANW*NCHUNK
  int n  = gid & 15;
  int t2 = gid >> 4;
  int j  = t2 / GROUPS;
  int cb = t2 - j * GROUPS;
  int c  = cb % DINNER;
  int b  = cb / DINNER;
  float Acn = -__expf(A_log[c * DSTATE + n]);
  float h = hin[gid];
  int mbase = b * SEQ_LEN + j * CHUNK;
#pragma unroll 2
  for (int s = 0; s < CHUNK; s++) {
    int m = mbase + s;
    float dtv = dt[(size_t)m * DINNER + c];
    float dxv = b2f(dtx[(size_t)m * DINNER + c]);
    float Bv  = b2f(xdb[(size_t)m * XPROJ_N + DTRANK + n]);
    float Cv  = b2f(xdb[(size_t)m * XPROJ_N + DTRANK + DSTATE + n]);
    float dA  = __expf(dtv * Acn);
    h = h * dA + dxv * Bv;
    float p = h * Cv;
    p += __shfl_xor(p, 8);
    p += __shfl_xor(p, 4);
    p += __shfl_xor(p, 2);
    p += __shfl_xor(p, 1);
    if (n == 0) y[(size_t)m * DINNER + c] = f2b(p);
  }
}

// ---------------- y = (y + D*xc) * silu(z)  -> bf16 (all-bf16 inputs) ----------------
__global__ __launch_bounds__(256) void k_ycomb(const bf16* __restrict__ y,
    const bf16* __restrict__ xcb, const bf16* __restrict__ xz,
    const float* __restrict__ D_ssm, bf16* __restrict__ ybf) {
  int id = blockIdx.x * 256 + threadIdx.x;          // MROWS*DINNER
  int m = id / DINNER, c = id - m * DINNER;
  float z = b2f(xz[(size_t)m * (2 * DINNER) + DINNER + c]);
  float sil = z / (1.f + __expf(-z));
  float v = (b2f(y[id]) + D_ssm[c] * b2f(xcb[id])) * sil;
  ybf[id] = f2b(v);
}

extern "C" void kernel_launch(void* const* d_in, const int* in_sizes, int n_in,
                              void* d_out, int out_size, void* d_ws, size_t ws_size,
                              hipStream_t stream) {
  const int*   tokens    = (const int*)  d_in[0];
  const float* embedding = (const float*)d_in[1];
  const float* head_bias = (const float*)d_in[2];
  const float* ln_g      = (const float*)d_in[3];
  const float* ln_b      = (const float*)d_in[4];
  const float* W_in      = (const float*)d_in[5];
  const float* conv_w    = (const float*)d_in[6];
  const float* conv_b    = (const float*)d_in[7];
  const float* W_xproj   = (const float*)d_in[8];
  const float* W_dt      = (const float*)d_in[9];
  const float* b_dt      = (const float*)d_in[10];
  const float* A_log     = (const float*)d_in[11];
  const float* D_ssm     = (const float*)d_in[12];
  const float* W_out     = (const float*)d_in[13];
  const float* norm_g    = (const float*)d_in[14];
  const float* norm_b    = (const float*)d_in[15];
  float* out = (float*)d_out;

  char* ws = (char*)d_ws;
  size_t off = 0;
  auto alloc = [&](size_t bytes) -> char* {
    char* p = ws + off;
    off = (off + bytes + 255) & ~(size_t)255;
    return p;
  };
  float*  x     = (float*) alloc((size_t)MROWS * DMODEL * 4);
  bf16*   xln   = (bf16*)  alloc((size_t)MROWS * DMODEL * 2);
  bf16*   xz    = (bf16*)  alloc((size_t)MROWS * 2 * DINNER * 2);
  bf16*   xcb   = (bf16*)  alloc((size_t)MROWS * DINNER * 2);
  bf16*   xdb   = (bf16*)  alloc((size_t)MROWS * XPROJ_N * 2);
  float*  xdbp  = (float*) alloc((size_t)XSPLIT * MROWS * XPROJ_N * 4);
  float*  dtf   = (float*) alloc((size_t)MROWS * DINNER * 4);
  bf16*   dtx   = (bf16*)  alloc((size_t)MROWS * DINNER * 2);
  bf16*   yraw  = (bf16*)  alloc((size_t)MROWS * DINNER * 2);
  bf16*   ybf   = (bf16*)  alloc((size_t)MROWS * DINNER * 2);
  float*  aprod = (float*) alloc((size_t)SCANW * NCHUNK * 4);
  float*  hend  = (float*) alloc((size_t)SCANW * NCHUNK * 4);
  float*  hin   = (float*) alloc((size_t)SCANW * NCHUNK * 4);
  ushort* ebf   = (ushort*)alloc((size_t)NVOCAB * DMODEL * 2);
  ushort* winb  = (ushort*)alloc((size_t)NLAYERS * 2 * DINNER * DMODEL * 2);
  ushort* wxpb  = (ushort*)alloc((size_t)NLAYERS * XPROJ_N * DINNER * 2);
  ushort* wdtb  = (ushort*)alloc((size_t)NLAYERS * DINNER * DTRANK * 2);
  ushort* woutb = (ushort*)alloc((size_t)NLAYERS * DMODEL * DINNER * 2);
  (void)ws_size; (void)in_sizes; (void)n_in; (void)out_size;

  // all weight conversions f32 -> bf16 in ONE dispatch
  k_cvt5<<<(CVT_E4 + 255) / 256, 256, 0, stream>>>(
      embedding, W_in, W_out, W_xproj, W_dt,
      ebf, winb, woutb, wxpb, wdtb);

  // fused embedding gather + layer-0 LN
  k_embed_ln<<<MROWS, 256, 0, stream>>>(tokens, embedding, x, xln, ln_g, ln_b);

  const int XDBN4 = MROWS * XPROJ_N / 4;          // 40960

  for (int L = 0; L < NLAYERS; L++) {
    if (L > 0)
      k_ln<<<MROWS, 256, 0, stream>>>(x, xln, ln_g + L * DMODEL, ln_b + L * DMODEL);

    // W_in GEMM -> bf16 xz (OMODE=2)
    k_gemm128<false, 2><<<dim3(MROWS / 128, (2 * DINNER) / 128), 512, 0, stream>>>(
        (const ushort*)xln, DMODEL,
        winb + (size_t)L * 2 * DINNER * DMODEL, DMODEL,
        (void*)xz, 2 * DINNER, nullptr, MROWS, 2 * DINNER, DMODEL);

    k_conv<<<MROWS * DINNER / 256, 256, 0, stream>>>(
        xz, conv_w + (size_t)L * DINNER * 4, conv_b + (size_t)L * DINNER, xcb);

    // xproj GEMM: split-K=8 into per-z f32 partial slices (no atomics), then sum->bf16
    k_gemm<3><<<dim3(MROWS / 64, 2, XSPLIT), 256, 0, stream>>>(
        (const ushort*)xcb, DINNER,
        wxpb + (size_t)L * XPROJ_N * DINNER, DINNER,
        (void*)xdbp, XPROJ_N, MROWS, XPROJ_N, DINNER,
        nullptr, nullptr, nullptr);
    k_xsum<<<(XDBN4 + 255) / 256, 256, 0, stream>>>(xdbp, (ushort*)xdb, XDBN4);

    // dt GEMM with fused softplus(+b_dt) and dtx = bf16(sp*xc)
    k_gemm<2><<<dim3(MROWS / 64, DINNER / 64), 256, 0, stream>>>(
        (const ushort*)xdb, XPROJ_N,
        wdtb + (size_t)L * DINNER * DTRANK, DTRANK,
        (void*)dtf, DINNER, MROWS, DINNER, DTRANK,
        b_dt + (size_t)L * DINNER, xcb, dtx);

    const float* Al = A_log + (size_t)L * DINNER * DSTATE;
    k_scan1<<<SCANW * NCHUNK / 256, 256, 0, stream>>>(dtf, dtx, xdb, Al, aprod, hend);
    k_scan2<<<SCANW / 256, 256, 0, stream>>>(aprod, hend, hin);
    k_scan3<<<SCANW * NCHUNK / 256, 256, 0, stream>>>(dtf, dtx, xdb, Al, hin, yraw);

    k_ycomb<<<MROWS * DINNER / 256, 256, 0, stream>>>(
        yraw, xcb, xz, D_ssm + (size_t)L * DINNER, ybf);

    // W_out GEMM: split-K=4, atomic f32 accumulate into residual x (OMODE=1)
    k_gemm128<false, 1><<<dim3(MROWS / 128, DMODEL / 128, 4), 512, 0, stream>>>(
        (const ushort*)ybf, DINNER,
        woutb + (size_t)L * DMODEL * DINNER, DINNER,
        (void*)x, DMODEL, nullptr, MROWS, DMODEL, DINNER);
  }

  k_ln<<<MROWS, 256, 0, stream>>>(x, xln, norm_g, norm_b);

  // LM head: 256x256-tile 16-wave GEMM (2048 x 32000 x 768), f32 out + bias
  k_gemmhead<true><<<dim3(MROWS / 256, NVOCAB / 256), 1024, 0, stream>>>(
      (const ushort*)xln, DMODEL,
      ebf, DMODEL,
      out, NVOCAB, head_bias, MROWS, NVOCAB, DMODEL);
}

// Round 11
// 963.109 us; speedup vs baseline: 1.0152x; 1.0152x over previous
//
#include <hip/hip_runtime.h>
#include <hip/hip_bf16.h>
#include <cstdint>
#include <cstddef>

#define SEQ_LEN 1024
#define NBATCH  2
#define MROWS   2048          // NBATCH*SEQ_LEN, row index m = b*SEQ_LEN + s
#define DMODEL  768
#define DINNER  1536
#define DTRANK  48
#define DSTATE  16
#define NLAYERS 4
#define NVOCAB  32000
#define XPROJ_N 80            // DTRANK + 2*DSTATE
#define NCHUNK  16
#define CHUNK   64            // SEQ_LEN / NCHUNK
#define GROUPS  (NBATCH * DINNER)          // 3072
#define SCANW   (GROUPS * DSTATE)          // 49152
#define XSPLIT  8             // xproj split-K factor

typedef __attribute__((ext_vector_type(4))) float f32x4;
typedef __attribute__((ext_vector_type(8))) short s16x8;
using bf16 = __hip_bfloat16;

__device__ __forceinline__ float b2f(bf16 v){ return __bfloat162float(v); }
__device__ __forceinline__ bf16  f2b(float v){ return __float2bfloat16(v); }
__device__ __forceinline__ short f2bs(float v){
  return (short)__builtin_bit_cast(unsigned short, __float2bfloat16(v));
}

// async global->LDS, 16B per lane; LDS dest = (wave-uniform base) + lane*16
__device__ __forceinline__ void glds16(const ushort* g, ushort* l) {
  __builtin_amdgcn_global_load_lds(
      (const __attribute__((address_space(1))) void*)g,
      (__attribute__((address_space(3))) void*)l,
      16, 0, 0);
}

// ---------------- merged f32 -> bf16 convert for all 5 weight tensors ----------------
#define CVT_E0 6144000            // emb     24,576,000 elems /4
#define CVT_E1 (CVT_E0 + 2359296) // + W_in   9,437,184 /4
#define CVT_E2 (CVT_E1 + 1179648) // + W_out  4,718,592 /4
#define CVT_E3 (CVT_E2 + 122880)  // + W_xproj  491,520 /4
#define CVT_E4 (CVT_E3 + 73728)   // + W_dt     294,912 /4
__global__ __launch_bounds__(256) void k_cvt5(
    const float* __restrict__ s0, const float* __restrict__ s1,
    const float* __restrict__ s2, const float* __restrict__ s3,
    const float* __restrict__ s4,
    ushort* __restrict__ d0, ushort* __restrict__ d1,
    ushort* __restrict__ d2, ushort* __restrict__ d3,
    ushort* __restrict__ d4)
{
  int i = blockIdx.x * 256 + threadIdx.x;
  const float* s; ushort* d; int base;
  if      (i < CVT_E0) { s = s0; d = d0; base = 0; }
  else if (i < CVT_E1) { s = s1; d = d1; base = CVT_E0; }
  else if (i < CVT_E2) { s = s2; d = d2; base = CVT_E1; }
  else if (i < CVT_E3) { s = s3; d = d3; base = CVT_E2; }
  else if (i < CVT_E4) { s = s4; d = d4; base = CVT_E3; }
  else return;
  int li = i - base;
  f32x4 v = *(const f32x4*)(s + (size_t)li * 4);
  ushort4 o;
  o.x = (ushort)f2bs(v[0]); o.y = (ushort)f2bs(v[1]);
  o.z = (ushort)f2bs(v[2]); o.w = (ushort)f2bs(v[3]);
  *(ushort4*)(d + (size_t)li * 4) = o;
}

// ---------------- sum XSPLIT f32 partials -> bf16 (xproj split-K reduce) ----------------
__global__ __launch_bounds__(256) void k_xsum(const float* __restrict__ p,
    ushort* __restrict__ out, int n4) {
  int i = blockIdx.x * 256 + threadIdx.x;
  if (i >= n4) return;
  f32x4 s = {};
#pragma unroll
  for (int z = 0; z < XSPLIT; z++) {
    f32x4 v = *(const f32x4*)(p + (size_t)z * (MROWS * XPROJ_N) + (size_t)i * 4);
    s[0] += v[0]; s[1] += v[1]; s[2] += v[2]; s[3] += v[3];
  }
  ushort4 o;
  o.x = (ushort)f2bs(s[0]); o.y = (ushort)f2bs(s[1]);
  o.z = (ushort)f2bs(s[2]); o.w = (ushort)f2bs(s[3]);
  *(ushort4*)(out + (size_t)i * 4) = o;
}

// ---------------- LN body shared by k_ln / k_embed_ln ----------------
__device__ __forceinline__ void ln_rows(const float v0[3], int t,
    const float* __restrict__ g, const float* __restrict__ b,
    bf16* __restrict__ outrow) {
  float s = 0.f, s2 = 0.f;
#pragma unroll
  for (int j = 0; j < 3; j++) { s += v0[j]; s2 += v0[j] * v0[j]; }
#pragma unroll
  for (int o = 32; o >= 1; o >>= 1) { s += __shfl_xor(s, o); s2 += __shfl_xor(s2, o); }
  __shared__ float red[8];
  int wave = t >> 6;
  if ((t & 63) == 0) { red[wave] = s; red[4 + wave] = s2; }
  __syncthreads();
  s  = red[0] + red[1] + red[2] + red[3];
  s2 = red[4] + red[5] + red[6] + red[7];
  float mean = s * (1.f / DMODEL);
  float var  = s2 * (1.f / DMODEL) - mean * mean;
  float rstd = rsqrtf(var + 1e-5f);
#pragma unroll
  for (int j = 0; j < 3; j++) {
    int d = t + j * 256;
    outrow[d] = f2b((v0[j] - mean) * rstd * g[d] + b[d]);
  }
}

// ---------------- LayerNorm over 768, f32 in -> bf16 out ----------------
__global__ __launch_bounds__(256) void k_ln(const float* __restrict__ x,
    bf16* __restrict__ out, const float* __restrict__ g, const float* __restrict__ b) {
  int m = blockIdx.x;
  const float* row = x + (size_t)m * DMODEL;
  int t = threadIdx.x;
  float v0[3];
#pragma unroll
  for (int j = 0; j < 3; j++) v0[j] = row[t + j * 256];
  ln_rows(v0, t, g, b, out + (size_t)m * DMODEL);
}

// ---------------- fused embedding gather + layer-0 LN ----------------
__global__ __launch_bounds__(256) void k_embed_ln(const int* __restrict__ tok,
    const float* __restrict__ emb, float* __restrict__ x,
    bf16* __restrict__ out, const float* __restrict__ g, const float* __restrict__ b) {
  int m = blockIdx.x;
  const float* row = emb + (size_t)tok[m] * DMODEL;
  int t = threadIdx.x;
  float v0[3];
#pragma unroll
  for (int j = 0; j < 3; j++) {
    v0[j] = row[t + j * 256];
    x[(size_t)m * DMODEL + t + j * 256] = v0[j];   // residual base
  }
  ln_rows(v0, t, g, b, out + (size_t)m * DMODEL);
}

// ---------------- 128x128 GEMM, 8 waves (W_in / W_out) ----------------
// C[M,N] = A[M,K] * B[N,K]^T. 512 threads, 8 waves as 4Mx2N, each wave 32x64.
// Depth-1 prefetch, counted vmcnt(2). OMODE: 0 f32, 1 f32 atomicAdd, 2 bf16.
template<bool HAS_BIAS, int OMODE>
__global__ __launch_bounds__(512, 4) void k_gemm128(
    const ushort* __restrict__ A, int lda,
    const ushort* __restrict__ B, int ldb,
    void* __restrict__ C, int ldc,
    const float* __restrict__ bias,
    int M, int N, int K)
{
  __shared__ ushort As[2][128 * 32];
  __shared__ ushort Bs[2][128 * 32];
  const int t = threadIdx.x;             // 0..511
  const int lane = t & 63;
  const int wave = t >> 6;               // 0..7
  const int tile_m = blockIdx.x * 128;
  const int tile_n = blockIdx.y * 128;
  const int kper = K / gridDim.z;
  const int kb = blockIdx.z * kper;
  const int ke = kb + kper;
  const int wr = (wave >> 1) * 32;       // 4 M-groups of 32
  const int wc = (wave & 1) * 64;        // 2 N-groups of 64

  f32x4 acc[2][4] = {};

  const int sr = wave * 16 + (lane >> 2);
  const int sc = (lane & 3) * 8;
  const ushort* gA = A + (size_t)(tile_m + sr) * lda + sc + kb;
  const ushort* gB = B + (size_t)(tile_n + sr) * ldb + sc + kb;

  const int fr = lane & 15;
  const int kk = (lane >> 4) * 8;

  auto stage = [&](int bb) {
    glds16(gA, &As[bb][wave * 512]);
    glds16(gB, &Bs[bb][wave * 512]);
    gA += 32; gB += 32;
  };

  stage(0);
  int cur = 0;

  for (int k0 = kb; k0 < ke; k0 += 32) {
    if (k0 + 32 < ke) {
      stage(cur ^ 1);                                   // prefetch next tile
      asm volatile("s_waitcnt vmcnt(2)" ::: "memory");  // drain current tile only
    } else {
      asm volatile("s_waitcnt vmcnt(0)" ::: "memory");
    }
    __builtin_amdgcn_s_barrier();

    s16x8 a[2], b[4];
#pragma unroll
    for (int m = 0; m < 2; m++)
      a[m] = *(const s16x8*)&As[cur][(wr + m * 16 + fr) * 32 + kk];
#pragma unroll
    for (int n = 0; n < 4; n++)
      b[n] = *(const s16x8*)&Bs[cur][(wc + n * 16 + fr) * 32 + kk];
#pragma unroll
    for (int m = 0; m < 2; m++)
#pragma unroll
      for (int n = 0; n < 4; n++)
        acc[m][n] = __builtin_amdgcn_mfma_f32_16x16x32_bf16(a[m], b[n], acc[m][n], 0, 0, 0);

    __builtin_amdgcn_s_barrier();
    cur ^= 1;
  }

  const int rq = (lane >> 4) * 4;
#pragma unroll
  for (int m = 0; m < 2; m++)
#pragma unroll
    for (int n = 0; n < 4; n++) {
      int colg = tile_n + wc + n * 16 + fr;
      float bv = HAS_BIAS ? bias[colg] : 0.f;
#pragma unroll
      for (int r = 0; r < 4; r++) {
        int rowg = tile_m + wr + m * 16 + rq + r;
        size_t idx = (size_t)rowg * ldc + colg;
        float v = acc[m][n][r] + bv;
        if constexpr (OMODE == 0) ((float*)C)[idx] = v;
        else if constexpr (OMODE == 1) atomicAdd((float*)C + idx, v);
        else ((bf16*)C)[idx] = f2b(v);
      }
    }
}

// ---------------- 256x256 head GEMM: deep-pipelined phase-split (T2+T4+T5) ----------------
// 512 thr, 8 waves (2Mx4N), wave = 128x64 output (acc 8x4). BK=32, 3 LDS
// buffers (96KB): stages issued TWO K-tiles ahead; ONE counted vmcnt(4) per
// K-tile boundary (never 0 mid-loop) -> each tile's 4 loads get a full
// K-tile of compute+barriers to land. Two sub-phases per K-tile (16 MFMA
// each, setprio-wrapped, ds_read/glds interleaved).
// LDS swizzle (T2, both-sides rule m173/m201): fragment reads at row-stride
// 64B are 8-16-way bank-conflicted (12.3M conflict-cycles measured). Fix:
// slot' = slot ^ ((row>>1)&3), applied to the per-lane GLOBAL source column
// during staging (LDS dest stays linear for global_load_lds) and to the
// ds_read address. 16-way -> 2-way (free, m136).
// vmcnt ledger (per wave, 4 glds/K-tile, FIFO per m135):
//   prologue: stage(0),stage(1) -> 8 out; vmcnt(4) = tile0 landed.
//   K-tile t: phases issue stage(t+2) (4 loads); boundary: out = t+1's 4 +
//   t+2's 4; vmcnt(4) drains the 4 oldest = t+1 landed. Buffer (t+2)%3 held
//   tile t-1, fully read before t's start barrier -> no WAR race.
template<bool HAS_BIAS>
__global__ __launch_bounds__(512, 2) void k_gemmhead(
    const ushort* __restrict__ A, int lda,
    const ushort* __restrict__ B, int ldb,
    float* __restrict__ C, int ldc,
    const float* __restrict__ bias,
    int M, int N, int K)
{
  __shared__ ushort As[3][256 * 32];     // 16 KB per buffer
  __shared__ ushort Bs[3][256 * 32];
  const int t = threadIdx.x;             // 0..511
  const int lane = t & 63;
  const int wave = t >> 6;               // 0..7
  const int tile_m = blockIdx.x * 256;
  const int tile_n = blockIdx.y * 256;
  const int wm = wave >> 2;              // 0..1 : rows wm*128..+127
  const int wn = wave & 3;               // 0..3 : cols wn*64..+63

  f32x4 acc[8][4] = {};

  // staging: block-wide load j covers rows j*128..+127 (wave w: +w*16+(l>>2)),
  // 4 lanes/row, source col chunk PRE-SWIZZLED: ((l&3) ^ ((l>>3)&3))*8.
  // Linear LDS dest = row*64B + (l&3)*16B == wavebase + l*16 (HW) -> content
  // of LDS slot c at row r is global chunk c ^ ((r>>1)&3).
  const int srow = wave * 16 + (lane >> 2);
  const int scol = ((lane & 3) ^ ((lane >> 3) & 3)) * 8;
  const ushort* gA0 = A + (size_t)(tile_m +       srow) * lda + scol;
  const ushort* gA1 = A + (size_t)(tile_m + 128 + srow) * lda + scol;
  const ushort* gB0 = B + (size_t)(tile_n +       srow) * ldb + scol;
  const ushort* gB1 = B + (size_t)(tile_n + 128 + srow) * ldb + scol;

  const int fr = lane & 15;
  // swizzled read chunk: q' = (lane>>4) ^ ((row>>1)&3); row bits below 16
  // contribute only fr -> q' = (lane>>4) ^ ((fr>>1)&3). In ushorts: *8.
  const int qs = (((lane >> 4) ^ ((fr >> 1) & 3)) * 8);

  auto stageA = [&](int bb) {
    glds16(gA0, &As[bb][wave * 512]);
    glds16(gA1, &As[bb][4096 + wave * 512]);
    gA0 += 32; gA1 += 32;
  };
  auto stageB = [&](int bb) {
    glds16(gB0, &Bs[bb][wave * 512]);
    glds16(gB1, &Bs[bb][4096 + wave * 512]);
    gB0 += 32; gB1 += 32;
  };

  const int NT = K / 32;                 // 24
  stageA(0); stageB(0);                  // prologue: tiles 0,1 in flight
  stageA(1); stageB(1);
  asm volatile("s_waitcnt vmcnt(4)" ::: "memory");   // tile 0 landed
  __builtin_amdgcn_s_barrier();

  int cur = 0;
  for (int tt = 0; tt < NT; ++tt) {
    const ushort* Ab = &As[cur][0];
    const ushort* Bb = &Bs[cur][0];
    int nxt = cur + 2; if (nxt >= 3) nxt -= 3;

    // ---- phase 1: read b[0..3], a[0..3]; issue stage A(t+2); MFMA m=0..3
    s16x8 a[4], b[4];
#pragma unroll
    for (int n = 0; n < 4; n++)
      b[n] = *(const s16x8*)&Bb[(wn * 64 + n * 16 + fr) * 32 + qs];
#pragma unroll
    for (int m = 0; m < 4; m++)
      a[m] = *(const s16x8*)&Ab[(wm * 128 + m * 16 + fr) * 32 + qs];
    if (tt + 2 < NT) stageA(nxt);
    __builtin_amdgcn_s_barrier();
    __builtin_amdgcn_s_setprio(1);
#pragma unroll
    for (int m = 0; m < 4; m++)
#pragma unroll
      for (int n = 0; n < 4; n++)
        acc[m][n] = __builtin_amdgcn_mfma_f32_16x16x32_bf16(a[m], b[n], acc[m][n], 0, 0, 0);
    __builtin_amdgcn_s_setprio(0);
    __builtin_amdgcn_s_barrier();

    // ---- phase 2: read a[4..7]; issue stage B(t+2); MFMA m=4..7
#pragma unroll
    for (int m = 0; m < 4; m++)
      a[m] = *(const s16x8*)&Ab[(wm * 128 + (m + 4) * 16 + fr) * 32 + qs];
    if (tt + 2 < NT) stageB(nxt);
    __builtin_amdgcn_s_barrier();
    __builtin_amdgcn_s_setprio(1);
#pragma unroll
    for (int m = 0; m < 4; m++)
#pragma unroll
      for (int n = 0; n < 4; n++)
        acc[m + 4][n] = __builtin_amdgcn_mfma_f32_16x16x32_bf16(a[m], b[n], acc[m + 4][n], 0, 0, 0);
    __builtin_amdgcn_s_setprio(0);

    // ---- K-tile boundary: tile t+1 must be landed; keep t+2's 4 in flight
    if (tt + 2 < NT) {
      asm volatile("s_waitcnt vmcnt(4)" ::: "memory");
    } else {
      asm volatile("s_waitcnt vmcnt(0)" ::: "memory");
    }
    __builtin_amdgcn_s_barrier();
    cur = cur + 1; if (cur == 3) cur = 0;
  }

  const int rq = (lane >> 4) * 4;
#pragma unroll
  for (int m = 0; m < 8; m++)
#pragma unroll
    for (int n = 0; n < 4; n++) {
      int colg = tile_n + wn * 64 + n * 16 + fr;
      float bv = HAS_BIAS ? bias[colg] : 0.f;
#pragma unroll
      for (int r = 0; r < 4; r++) {
        int rowg = tile_m + wm * 128 + m * 16 + rq + r;
        C[(size_t)rowg * ldc + colg] = acc[m][n][r] + bv;
      }
    }
}

// ---------------- small GEMM (bounds-checked 64x64): C = A * W^T, bf16 inputs ----------------
// MODE: 0 = bf16 out
//       2 = dt-fused: sp=softplus(acc+bias[col]) -> dtf[idx]=sp (f32),
//           dtx[idx]=bf16(sp*xcb[idx])
//       3 = f32 partial out at slice blockIdx.z (xproj split-K; stride MROWS*XPROJ_N)
template<int MODE>
__global__ __launch_bounds__(256) void k_gemm(
    const ushort* __restrict__ A, int lda,
    const ushort* __restrict__ W, int ldw,
    void* __restrict__ Cout, int ldc,
    int M, int N, int K,
    const float* __restrict__ bias,
    const bf16* __restrict__ xcb,
    bf16* __restrict__ dtxp)
{
  __shared__ ushort As[64][40];
  __shared__ ushort Ws[64][40];
  const int tile_m = blockIdx.x * 64;
  const int tile_n = blockIdx.y * 64;
  const int t = threadIdx.x;
  const int lane = t & 63;
  const int wave = t >> 6;
  const int wr = (wave >> 1) * 32;
  const int wc = (wave & 1) * 32;
  f32x4 acc[2][2] = {};

  const int kper = ((K + gridDim.z - 1) / gridDim.z + 31) & ~31;
  const int kb = blockIdx.z * kper;
  int ke = kb + kper; if (ke > K) ke = K;

  const int srow = t >> 2;
  const int scol = (t & 3) * 8;

  for (int k0 = kb; k0 < ke; k0 += 32) {
    {
      int gm = tile_m + srow, gk = k0 + scol;
      s16x8 v = {};
      if (gm < M) {
        if (gk + 8 <= K) v = *(const s16x8*)(A + (size_t)gm * lda + gk);
        else {
#pragma unroll
          for (int j = 0; j < 8; j++) if (gk + j < K) v[j] = (short)A[(size_t)gm * lda + gk + j];
        }
      }
      *(s16x8*)&As[srow][scol] = v;
    }
    {
      int gn = tile_n + srow, gk = k0 + scol;
      s16x8 v = {};
      if (gn < N) {
        if (gk + 8 <= K) v = *(const s16x8*)(W + (size_t)gn * ldw + gk);
        else {
#pragma unroll
          for (int j = 0; j < 8; j++) if (gk + j < K) v[j] = (short)W[(size_t)gn * ldw + gk + j];
        }
      }
      *(s16x8*)&Ws[srow][scol] = v;
    }
    __syncthreads();
    const int kk = (lane >> 4) * 8;
    const int fr = lane & 15;
    s16x8 a0 = *(const s16x8*)&As[wr + fr][kk];
    s16x8 a1 = *(const s16x8*)&As[wr + 16 + fr][kk];
    s16x8 b0 = *(const s16x8*)&Ws[wc + fr][kk];
    s16x8 b1 = *(const s16x8*)&Ws[wc + 16 + fr][kk];
    acc[0][0] = __builtin_amdgcn_mfma_f32_16x16x32_bf16(a0, b0, acc[0][0], 0, 0, 0);
    acc[0][1] = __builtin_amdgcn_mfma_f32_16x16x32_bf16(a0, b1, acc[0][1], 0, 0, 0);
    acc[1][0] = __builtin_amdgcn_mfma_f32_16x16x32_bf16(a1, b0, acc[1][0], 0, 0, 0);
    acc[1][1] = __builtin_amdgcn_mfma_f32_16x16x32_bf16(a1, b1, acc[1][1], 0, 0, 0);
    __syncthreads();
  }

  const int fr = lane & 15;
  const int rq = (lane >> 4) * 4;
#pragma unroll
  for (int i = 0; i < 2; i++)
#pragma unroll
    for (int j = 0; j < 2; j++) {
      int colg = tile_n + wc + j * 16 + fr;
#pragma unroll
      for (int r = 0; r < 4; r++) {
        int rowg = tile_m + wr + i * 16 + rq + r;
        if (rowg < M && colg < N) {
          float v = acc[i][j][r];
          size_t idx = (size_t)rowg * ldc + colg;
          if constexpr (MODE == 0) {
            ((bf16*)Cout)[idx] = f2b(v);
          } else if constexpr (MODE == 2) {
            v += bias[colg];
            float sp = (v > 20.f) ? v : log1pf(__expf(v));
            ((float*)Cout)[idx] = sp;
            dtxp[idx] = f2b(sp * b2f(xcb[idx]));
          } else {
            ((float*)Cout)[(size_t)blockIdx.z * (MROWS * XPROJ_N) + idx] = v;
          }
        }
      }
    }
}

// ---------------- causal depthwise conv (D_CONV=4) + bias + silu; bf16 in/out ----------------
__global__ __launch_bounds__(256) void k_conv(const bf16* __restrict__ xz,
    const float* __restrict__ w, const float* __restrict__ cb,
    bf16* __restrict__ xcb) {
  int id = blockIdx.x * 256 + threadIdx.x;          // MROWS*DINNER
  int m = id / DINNER, c = id - m * DINNER;
  int s = m & (SEQ_LEN - 1);
  float acc = cb[c];
#pragma unroll
  for (int k = 0; k < 4; k++) {
    int sp = s - 3 + k;
    if (sp >= 0) acc += w[c * 4 + k] * b2f(xz[(size_t)(m - 3 + k) * (2 * DINNER) + c]);
  }
  float sil = acc / (1.f + __expf(-acc));
  xcb[id] = f2b(sil);
}

// ---------------- chunked selective scan (3 kernels; per-wave-coalesced layout) ----------------
__global__ __launch_bounds__(256) void k_scan1(const float* __restrict__ dt,
    const bf16* __restrict__ dtx, const bf16* __restrict__ xdb,
    const float* __restrict__ A_log, float* __restrict__ aprod,
    float* __restrict__ hend) {
  int gid = blockIdx.x * 256 + threadIdx.x;     // SCANW*NCHUNK
  int n  = gid & 15;
  int t2 = gid >> 4;
  int j  = t2 / GROUPS;
  int cb = t2 - j * GROUPS;
  int c  = cb % DINNER;
  int b  = cb / DINNER;
  float Acn = -__expf(A_log[c * DSTATE + n]);
  float h = 0.f, ap = 1.f;
  int mbase = b * SEQ_LEN + j * CHUNK;
#pragma unroll 4
  for (int s = 0; s < CHUNK; s++) {
    int m = mbase + s;
    float dtv = dt[(size_t)m * DINNER + c];
    float dxv = b2f(dtx[(size_t)m * DINNER + c]);
    float Bv  = b2f(xdb[(size_t)m * XPROJ_N + DTRANK + n]);
    float dA  = __expf(dtv * Acn);
    h = h * dA + dxv * Bv;
    ap *= dA;
  }
  aprod[gid] = ap;
  hend[gid]  = h;
}

__global__ __launch_bounds__(256) void k_scan2(const float* __restrict__ aprod,
    const float* __restrict__ hend, float* __restrict__ hin) {
  int idx = blockIdx.x * 256 + threadIdx.x;     // SCANW
  float h = 0.f;
#pragma unroll
  for (int j = 0; j < NCHUNK; j++) {
    hin[(size_t)j * SCANW + idx] = h;
    h = aprod[(size_t)j * SCANW + idx] * h + hend[(size_t)j * SCANW + idx];
  }
}

__global__ __launch_bounds__(256) void k_scan3(const float* __restrict__ dt,
    const bf16* __restrict__ dtx, const bf16* __restrict__ xdb,
    const float* __restrict__ A_log, const float* __restrict__ hin,
    bf16* __restrict__ y) {
  int gid = blockIdx.x * 256 + threadIdx.x;     // SCANW*NCHUNK
  int n  = gid & 15;
  int t2 = gid >> 4;
  int j  = t2 / GROUPS;
  int cb = t2 - j * GROUPS;
  int c  = cb % DINNER;
  int b  = cb / DINNER;
  float Acn = -__expf(A_log[c * DSTATE + n]);
  float h = hin[gid];
  int mbase = b * SEQ_LEN + j * CHUNK;
#pragma unroll 2
  for (int s = 0; s < CHUNK; s++) {
    int m = mbase + s;
    float dtv = dt[(size_t)m * DINNER + c];
    float dxv = b2f(dtx[(size_t)m * DINNER + c]);
    float Bv  = b2f(xdb[(size_t)m * XPROJ_N + DTRANK + n]);
    float Cv  = b2f(xdb[(size_t)m * XPROJ_N + DTRANK + DSTATE + n]);
    float dA  = __expf(dtv * Acn);
    h = h * dA + dxv * Bv;
    float p = h * Cv;
    p += __shfl_xor(p, 8);
    p += __shfl_xor(p, 4);
    p += __shfl_xor(p, 2);
    p += __shfl_xor(p, 1);
    if (n == 0) y[(size_t)m * DINNER + c] = f2b(p);
  }
}

// ---------------- y = (y + D*xc) * silu(z)  -> bf16 (all-bf16 inputs) ----------------
__global__ __launch_bounds__(256) void k_ycomb(const bf16* __restrict__ y,
    const bf16* __restrict__ xcb, const bf16* __restrict__ xz,
    const float* __restrict__ D_ssm, bf16* __restrict__ ybf) {
  int id = blockIdx.x * 256 + threadIdx.x;          // MROWS*DINNER
  int m = id / DINNER, c = id - m * DINNER;
  float z = b2f(xz[(size_t)m * (2 * DINNER) + DINNER + c]);
  float sil = z / (1.f + __expf(-z));
  float v = (b2f(y[id]) + D_ssm[c] * b2f(xcb[id])) * sil;
  ybf[id] = f2b(v);
}

extern "C" void kernel_launch(void* const* d_in, const int* in_sizes, int n_in,
                              void* d_out, int out_size, void* d_ws, size_t ws_size,
                              hipStream_t stream) {
  const int*   tokens    = (const int*)  d_in[0];
  const float* embedding = (const float*)d_in[1];
  const float* head_bias = (const float*)d_in[2];
  const float* ln_g      = (const float*)d_in[3];
  const float* ln_b      = (const float*)d_in[4];
  const float* W_in      = (const float*)d_in[5];
  const float* conv_w    = (const float*)d_in[6];
  const float* conv_b    = (const float*)d_in[7];
  const float* W_xproj   = (const float*)d_in[8];
  const float* W_dt      = (const float*)d_in[9];
  const float* b_dt      = (const float*)d_in[10];
  const float* A_log     = (const float*)d_in[11];
  const float* D_ssm     = (const float*)d_in[12];
  const float* W_out     = (const float*)d_in[13];
  const float* norm_g    = (const float*)d_in[14];
  const float* norm_b    = (const float*)d_in[15];
  float* out = (float*)d_out;

  char* ws = (char*)d_ws;
  size_t off = 0;
  auto alloc = [&](size_t bytes) -> char* {
    char* p = ws + off;
    off = (off + bytes + 255) & ~(size_t)255;
    return p;
  };
  float*  x     = (float*) alloc((size_t)MROWS * DMODEL * 4);
  bf16*   xln   = (bf16*)  alloc((size_t)MROWS * DMODEL * 2);
  bf16*   xz    = (bf16*)  alloc((size_t)MROWS * 2 * DINNER * 2);
  bf16*   xcb   = (bf16*)  alloc((size_t)MROWS * DINNER * 2);
  bf16*   xdb   = (bf16*)  alloc((size_t)MROWS * XPROJ_N * 2);
  float*  xdbp  = (float*) alloc((size_t)XSPLIT * MROWS * XPROJ_N * 4);
  float*  dtf   = (float*) alloc((size_t)MROWS * DINNER * 4);
  bf16*   dtx   = (bf16*)  alloc((size_t)MROWS * DINNER * 2);
  bf16*   yraw  = (bf16*)  alloc((size_t)MROWS * DINNER * 2);
  bf16*   ybf   = (bf16*)  alloc((size_t)MROWS * DINNER * 2);
  float*  aprod = (float*) alloc((size_t)SCANW * NCHUNK * 4);
  float*  hend  = (float*) alloc((size_t)SCANW * NCHUNK * 4);
  float*  hin   = (float*) alloc((size_t)SCANW * NCHUNK * 4);
  ushort* ebf   = (ushort*)alloc((size_t)NVOCAB * DMODEL * 2);
  ushort* winb  = (ushort*)alloc((size_t)NLAYERS * 2 * DINNER * DMODEL * 2);
  ushort* wxpb  = (ushort*)alloc((size_t)NLAYERS * XPROJ_N * DINNER * 2);
  ushort* wdtb  = (ushort*)alloc((size_t)NLAYERS * DINNER * DTRANK * 2);
  ushort* woutb = (ushort*)alloc((size_t)NLAYERS * DMODEL * DINNER * 2);
  (void)ws_size; (void)in_sizes; (void)n_in; (void)out_size;

  // all weight conversions f32 -> bf16 in ONE dispatch
  k_cvt5<<<(CVT_E4 + 255) / 256, 256, 0, stream>>>(
      embedding, W_in, W_out, W_xproj, W_dt,
      ebf, winb, woutb, wxpb, wdtb);

  // fused embedding gather + layer-0 LN
  k_embed_ln<<<MROWS, 256, 0, stream>>>(tokens, embedding, x, xln, ln_g, ln_b);

  const int XDBN4 = MROWS * XPROJ_N / 4;          // 40960

  for (int L = 0; L < NLAYERS; L++) {
    if (L > 0)
      k_ln<<<MROWS, 256, 0, stream>>>(x, xln, ln_g + L * DMODEL, ln_b + L * DMODEL);

    // W_in GEMM -> bf16 xz (OMODE=2)
    k_gemm128<false, 2><<<dim3(MROWS / 128, (2 * DINNER) / 128), 512, 0, stream>>>(
        (const ushort*)xln, DMODEL,
        winb + (size_t)L * 2 * DINNER * DMODEL, DMODEL,
        (void*)xz, 2 * DINNER, nullptr, MROWS, 2 * DINNER, DMODEL);

    k_conv<<<MROWS * DINNER / 256, 256, 0, stream>>>(
        xz, conv_w + (size_t)L * DINNER * 4, conv_b + (size_t)L * DINNER, xcb);

    // xproj GEMM: split-K=8 into per-z f32 partial slices (no atomics), then sum->bf16
    k_gemm<3><<<dim3(MROWS / 64, 2, XSPLIT), 256, 0, stream>>>(
        (const ushort*)xcb, DINNER,
        wxpb + (size_t)L * XPROJ_N * DINNER, DINNER,
        (void*)xdbp, XPROJ_N, MROWS, XPROJ_N, DINNER,
        nullptr, nullptr, nullptr);
    k_xsum<<<(XDBN4 + 255) / 256, 256, 0, stream>>>(xdbp, (ushort*)xdb, XDBN4);

    // dt GEMM with fused softplus(+b_dt) and dtx = bf16(sp*xc)
    k_gemm<2><<<dim3(MROWS / 64, DINNER / 64), 256, 0, stream>>>(
        (const ushort*)xdb, XPROJ_N,
        wdtb + (size_t)L * DINNER * DTRANK, DTRANK,
        (void*)dtf, DINNER, MROWS, DINNER, DTRANK,
        b_dt + (size_t)L * DINNER, xcb, dtx);

    const float* Al = A_log + (size_t)L * DINNER * DSTATE;
    k_scan1<<<SCANW * NCHUNK / 256, 256, 0, stream>>>(dtf, dtx, xdb, Al, aprod, hend);
    k_scan2<<<SCANW / 256, 256, 0, stream>>>(aprod, hend, hin);
    k_scan3<<<SCANW * NCHUNK / 256, 256, 0, stream>>>(dtf, dtx, xdb, Al, hin, yraw);

    k_ycomb<<<MROWS * DINNER / 256, 256, 0, stream>>>(
        yraw, xcb, xz, D_ssm + (size_t)L * DINNER, ybf);

    // W_out GEMM: split-K=4, atomic f32 accumulate into residual x (OMODE=1)
    k_gemm128<false, 1><<<dim3(MROWS / 128, DMODEL / 128, 4), 512, 0, stream>>>(
        (const ushort*)ybf, DINNER,
        woutb + (size_t)L * DMODEL * DINNER, DINNER,
        (void*)x, DMODEL, nullptr, MROWS, DMODEL, DINNER);
  }

  k_ln<<<MROWS, 256, 0, stream>>>(x, xln, norm_g, norm_b);

  // LM head: 256x256 deep-pipelined GEMM (2048 x 32000 x 768), f32 out + bias
  k_gemmhead<true><<<dim3(MROWS / 256, NVOCAB / 256), 512, 0, stream>>>(
      (const ushort*)xln, DMODEL,
      ebf, DMODEL,
      out, NVOCAB, head_bias, MROWS, NVOCAB, DMODEL);
}